// Round 16
// baseline (172.161 us; speedup 1.0000x reference)
//
#include <hip/hip_runtime.h>
#include <hip/hip_bf16.h>
#include <stdint.h>

// Problem dims (fixed by reference)
#define NB 16384
#define ND 1024
#define NH 2048
#define NE 8
#define NC 3
#define MAXWL 136  // max active (e,mt) 128-row tiles: 16384/128 + 8

typedef __attribute__((ext_vector_type(8))) short short8;
typedef __attribute__((ext_vector_type(4))) short short4v;
typedef __attribute__((ext_vector_type(4))) float f32x4;

// fp32 -> bf16 round-to-nearest-even
__device__ __forceinline__ unsigned short f2bf(float f) {
  union { float f; unsigned int u; } v; v.f = f;
  unsigned int u = v.u;
  return (unsigned short)((u + 0x7fffu + ((u >> 16) & 1u)) >> 16);
}

// async global->LDS, 16B per lane (LDS dest linear in lane order)
__device__ __forceinline__ void glds16(const void* g, void* l) {
  __builtin_amdgcn_global_load_lds(
      (const __attribute__((address_space(1))) void*)g,
      (__attribute__((address_space(3))) void*)l,
      16, 0, 0);
}

// ---------------------------------------------------------------------------
// Kernel 1: router. FOUR rows per wave: 16 x-loads in flight/thread, one Wr
// read serves 4 rows' FMAs. Fused x->bf16. fp32 logits (argmax must match
// numpy fp32). No atomics.
// ---------------------------------------------------------------------------
__global__ __launch_bounds__(256) void router_kernel(
    const float* __restrict__ x, const float* __restrict__ Wr,
    const float* __restrict__ br, unsigned short* __restrict__ xb,
    int* __restrict__ topics) {
  int w = threadIdx.x >> 6, lane = threadIdx.x & 63;
  int row0 = blockIdx.x * 16 + w * 4;
  const float* xr[4];
  unsigned short* xbr[4];
#pragma unroll
  for (int r = 0; r < 4; ++r) {
    xr[r] = x + (size_t)(row0 + r) * ND;
    xbr[r] = xb + (size_t)(row0 + r) * ND;
  }
  f32x4 xv[4][4];
#pragma unroll
  for (int r = 0; r < 4; ++r)
#pragma unroll
    for (int i = 0; i < 4; ++i)
      xv[r][i] = *(const f32x4*)(xr[r] + i * 256 + lane * 4);
  float p[4][NE];
#pragma unroll
  for (int r = 0; r < 4; ++r)
#pragma unroll
    for (int e = 0; e < NE; ++e) p[r][e] = 0.f;
#pragma unroll
  for (int i = 0; i < 4; ++i) {
    int k0 = i * 256 + lane * 4;
#pragma unroll
    for (int r = 0; r < 4; ++r) {
      short4v s;
#pragma unroll
      for (int j = 0; j < 4; ++j) s[j] = (short)f2bf(xv[r][i][j]);
      *(short4v*)(xbr[r] + k0) = s;  // coalesced 8B/lane
    }
#pragma unroll
    for (int j = 0; j < 4; ++j) {
      const f32x4* wp = (const f32x4*)(Wr + (size_t)(k0 + j) * NE);
      f32x4 wa = wp[0], wb = wp[1];  // one Wr read serves FOUR rows
#pragma unroll
      for (int r = 0; r < 4; ++r) {
        float a = xv[r][i][j];
        p[r][0] = fmaf(a, wa[0], p[r][0]);
        p[r][1] = fmaf(a, wa[1], p[r][1]);
        p[r][2] = fmaf(a, wa[2], p[r][2]);
        p[r][3] = fmaf(a, wa[3], p[r][3]);
        p[r][4] = fmaf(a, wb[0], p[r][4]);
        p[r][5] = fmaf(a, wb[1], p[r][5]);
        p[r][6] = fmaf(a, wb[2], p[r][6]);
        p[r][7] = fmaf(a, wb[3], p[r][7]);
      }
    }
  }
#pragma unroll
  for (int r = 0; r < 4; ++r)
#pragma unroll
    for (int e = 0; e < NE; ++e) {
#pragma unroll
      for (int d = 1; d < 64; d <<= 1) p[r][e] += __shfl_xor(p[r][e], d);
    }
  if (lane == 0) {
#pragma unroll
    for (int r = 0; r < 4; ++r) {
      float best = -1e30f;
      int bi = 0;
#pragma unroll
      for (int e = 0; e < NE; ++e) {
        float v = p[r][e] + br[e];
        if (v > best) { best = v; bi = e; }  // strict > : numpy argmax
      }
      topics[row0 + r] = bi;
    }
  }
}

// ---------------------------------------------------------------------------
// Kernel 2: FUSED ranker + W1 transpose (round-15 structure, kept).
//   blocks 0..511 : W1 [E][D][H] f32 -> W1T [E][H][D] bf16, 8 h-tiles each.
//   block  512    : ranker — packed-u16 Hillis-Steele scan -> stable rank
//                   -> perm scatter + counts/offsets + worklist.
// ---------------------------------------------------------------------------
__global__ __launch_bounds__(1024) void ranker_w1t_kernel(
    const int* __restrict__ topics, const float* __restrict__ W1,
    unsigned short* __restrict__ w1t, int* __restrict__ perm,
    int* __restrict__ counts, int* __restrict__ offsets,
    int* __restrict__ worklist, int* __restrict__ n_wl) {
  __shared__ __align__(16) char smem[8 * 64 * 67 * 2];  // 68.6KB, aliased
  __shared__ int soff[NE];
  int tid = threadIdx.x;

  if (blockIdx.x < 512) {
    // ---- W1 transpose+convert: eight 64x64 tiles (same e,kb; hb0..hb0+7) --
    unsigned short(*sbuf_t)[64][67] = (unsigned short(*)[64][67])smem;
    int bid = blockIdx.x;
    int e = bid >> 6;          // 64 blocks/expert
    int rem = bid & 63;
    int kb = rem >> 2;         // 16 k-tiles
    int hb0 = (rem & 3) * 8;   // 4 groups of 8 h-tiles
    int kl = tid >> 4;
    int h0 = (tid & 15) * 4;
    const float* src = W1 + ((size_t)e * ND + kb * 64) * NH + hb0 * 64;
    f32x4 v[8];
#pragma unroll
    for (int q = 0; q < 8; ++q)  // 8 independent loads in flight
      v[q] = *(const f32x4*)(src + (size_t)kl * NH + q * 64 + h0);
#pragma unroll
    for (int q = 0; q < 8; ++q) {
#pragma unroll
      for (int j = 0; j < 4; ++j) sbuf_t[q][kl][h0 + j] = f2bf(v[q][j]);
    }
    __syncthreads();
    // store: 4 (tile,pos) pairs per thread; wave writes 8 rows x 128B
    // contiguous segments (16B/lane coalesced).
#pragma unroll
    for (int s = 0; s < 4; ++s) {
      int flat = s * 1024 + tid;
      int q = flat >> 9;         // 0..7
      int idx = flat & 511;
      int hl = idx >> 3;         // 0..63
      int c8 = (idx & 7) * 8;    // k-chunk base
      short8 sv;
#pragma unroll
      for (int j = 0; j < 8; ++j) sv[j] = (short)sbuf_t[q][c8 + j][hl];
      unsigned short* dst =
          w1t + ((size_t)e * NH + (hb0 + q) * 64 + hl) * ND + kb * 64 + c8;
      *(short8*)dst = sv;  // 16B/lane
    }
    return;
  }

  // ---- ranker (block 512; scan buffer aliases smem) ----
  uint4* sbuf = (uint4*)smem;  // 16KB of the 68.6KB region
  int t[16];
  const int4* tp = (const int4*)(topics + tid * 16);
#pragma unroll
  for (int i = 0; i < 4; ++i) {
    int4 v = tp[i];
    t[i * 4 + 0] = v.x; t[i * 4 + 1] = v.y;
    t[i * 4 + 2] = v.z; t[i * 4 + 3] = v.w;
  }
  int h[NE] = {0, 0, 0, 0, 0, 0, 0, 0};
#pragma unroll
  for (int i = 0; i < 16; ++i) {
#pragma unroll
    for (int q = 0; q < NE; ++q) h[q] += (t[i] == q);
  }
  uint4 pk;
  pk.x = (unsigned)h[0] | ((unsigned)h[1] << 16);
  pk.y = (unsigned)h[2] | ((unsigned)h[3] << 16);
  pk.z = (unsigned)h[4] | ((unsigned)h[5] << 16);
  pk.w = (unsigned)h[6] | ((unsigned)h[7] << 16);
  uint4 own = pk;
  sbuf[tid] = pk;
  __syncthreads();
  for (int d = 1; d < 1024; d <<= 1) {
    uint4 v = {0u, 0u, 0u, 0u};
    if (tid >= d) v = sbuf[tid - d];
    __syncthreads();
    pk.x += v.x; pk.y += v.y; pk.z += v.z; pk.w += v.w;
    sbuf[tid] = pk;
    __syncthreads();
  }
  if (tid == 0) {
    uint4 tot = sbuf[1023];
    int c[NE] = {(int)(tot.x & 0xffff), (int)(tot.x >> 16),
                 (int)(tot.y & 0xffff), (int)(tot.y >> 16),
                 (int)(tot.z & 0xffff), (int)(tot.z >> 16),
                 (int)(tot.w & 0xffff), (int)(tot.w >> 16)};
    int s = 0, nw = 0;
    for (int e = 0; e < NE; ++e) {
      counts[e] = c[e];
      offsets[e] = s;
      soff[e] = s;
      s += c[e];
      for (int mt = 0; mt * 128 < c[e]; ++mt) worklist[nw++] = (e << 16) | mt;
    }
    *n_wl = nw;
  }
  __syncthreads();
  uint4 ex;
  ex.x = pk.x - own.x; ex.y = pk.y - own.y;
  ex.z = pk.z - own.z; ex.w = pk.w - own.w;
  int r[NE] = {soff[0] + (int)(ex.x & 0xffff), soff[1] + (int)(ex.x >> 16),
               soff[2] + (int)(ex.y & 0xffff), soff[3] + (int)(ex.y >> 16),
               soff[4] + (int)(ex.z & 0xffff), soff[5] + (int)(ex.z >> 16),
               soff[6] + (int)(ex.w & 0xffff), soff[7] + (int)(ex.w >> 16)};
#pragma unroll
  for (int i = 0; i < 16; ++i) {
    int e = t[i];
    int pos = 0;
#pragma unroll
    for (int q = 0; q < NE; ++q) pos = (e == q) ? r[q] : pos;
    perm[pos] = tid * 16 + i;
#pragma unroll
    for (int q = 0; q < NE; ++q) r[q] += (e == q);
  }
}

// ---------------------------------------------------------------------------
// Kernel 3: fused gathered GEMM + bias/relu + W2 reduce -> PARTIALS.
// Counted-vmcnt pipeline, round-16 phase reorder: reads -> MFMA (compiler's
// FINE-GRAINED lgkmcnt interleaves ds_read latency under MFMA issue; the
// old blanket lgkmcnt(0)+sched_barrier BEFORE the MFMA cluster serialized
// all 8 ds_reads ahead of the first MFMA every phase) -> lgkmcnt(0) (free
// by now; needed so the all-read barrier guarantees no outstanding reads
// before any wave overwrites the buffer) -> s_barrier -> STAGE(t+2) ->
// vmcnt(8) (retires other buffer's stage) -> s_barrier.
// 128x128 tile, BK=64, 16 K-tiles, 4 waves; swizzle slot(r,c)=chunk c^(r&7).
// ---------------------------------------------------------------------------
#define MF(a, b, c) __builtin_amdgcn_mfma_f32_16x16x32_bf16((a), (b), (c), 0, 0, 0)

#define STAGE(AS, BS, kt)                                         \
  do {                                                            \
    _Pragma("unroll") for (int i_ = 0; i_ < 4; ++i_) {            \
      glds16(aptr[i_] + (kt), (char*)(AS) + (i_ * 256 + t) * 16); \
      glds16(bptr[i_] + (kt), (char*)(BS) + (i_ * 256 + t) * 16); \
    }                                                             \
  } while (0)

#define PHASE(AS, BS, KT2)                                            \
  {                                                                   \
    short8 af_[2][4], bf_[2][4];                                      \
    _Pragma("unroll") for (int kk_ = 0; kk_ < 2; ++kk_) {             \
      int ch_ = ((kk_ * 4 + g) ^ sx) * 8;                             \
      _Pragma("unroll") for (int m_ = 0; m_ < 4; ++m_)                \
          af_[kk_][m_] = *(const short8*)&(AS)[arow + m_ * 1024 + ch_]; \
      _Pragma("unroll") for (int n_ = 0; n_ < 4; ++n_)                \
          bf_[kk_][n_] = *(const short8*)&(BS)[brow + n_ * 1024 + ch_]; \
    }                                                                 \
    __builtin_amdgcn_s_setprio(1);                                    \
    _Pragma("unroll") for (int kk_ = 0; kk_ < 2; ++kk_)               \
        _Pragma("unroll") for (int m_ = 0; m_ < 4; ++m_)              \
            _Pragma("unroll") for (int n_ = 0; n_ < 4; ++n_)          \
                acc[m_][n_] = MF(af_[kk_][m_], bf_[kk_][n_], acc[m_][n_]); \
    __builtin_amdgcn_s_setprio(0);                                    \
    asm volatile("s_waitcnt lgkmcnt(0)" ::: "memory");                \
    __builtin_amdgcn_s_barrier();                                     \
    STAGE(AS, BS, KT2);                                               \
    asm volatile("s_waitcnt vmcnt(8)" ::: "memory");                  \
    __builtin_amdgcn_s_barrier();                                     \
  }

__global__ __launch_bounds__(256, 2) void moe_gemm_kernel(
    const unsigned short* __restrict__ xb, const unsigned short* __restrict__ w1t,
    const float* __restrict__ b1, const float* __restrict__ W2,
    const int* __restrict__ perm, const int* __restrict__ counts,
    const int* __restrict__ offsets, const int* __restrict__ worklist,
    const int* __restrict__ n_wl, float* __restrict__ partial) {
  int nt = blockIdx.x & 15;  // B panel; XCD = bid%8 -> B L2-local
  int wi = blockIdx.x >> 4;
  if (wi >= *n_wl) return;
  int item = worklist[wi];
  int e = item >> 16;
  int mt = item & 0xffff;
  int cnt = counts[e];
  int off = offsets[e];
  int t = threadIdx.x;
  int lane = t & 63;
  int w = t >> 6, wr = w >> 1, wc = w & 1;

  __shared__ int ridx[128];
  __shared__ unsigned short As0[128 * 64];  // slot(r,c) holds chunk c^(r&7)
  __shared__ unsigned short Bs0[128 * 64];
  __shared__ unsigned short As1[128 * 64];
  __shared__ unsigned short Bs1[128 * 64];

  if (t < 128) {
    int m = mt * 128 + t;
    ridx[t] = perm[off + (m < cnt ? m : cnt - 1)];
  }

  // Epilogue weights loaded & pinned BEFORE the __syncthreads drain, so the
  // K-loop's counted vmcnt(8) sees ONLY glds16 ops in the vmcnt queue.
  int cg = lane & 15;
  int g = lane >> 4;
  float b1v[4];
  float w2v[4][3];
#pragma unroll
  for (int n = 0; n < 4; ++n) {
    int col = nt * 128 + wc * 64 + n * 16 + cg;
    b1v[n] = b1[e * NH + col];
    const float* w2p = W2 + ((size_t)e * NH + col) * NC;
    w2v[n][0] = w2p[0];
    w2v[n][1] = w2p[1];
    w2v[n][2] = w2p[2];
  }
  asm volatile("" ::"v"(b1v[0]), "v"(b1v[1]), "v"(b1v[2]), "v"(b1v[3]),
               "v"(w2v[0][0]), "v"(w2v[0][1]), "v"(w2v[0][2]), "v"(w2v[1][0]),
               "v"(w2v[1][1]), "v"(w2v[1][2]), "v"(w2v[2][0]), "v"(w2v[2][1]),
               "v"(w2v[2][2]), "v"(w2v[3][0]), "v"(w2v[3][1]), "v"(w2v[3][2]));
  __syncthreads();  // full drain: vmcnt queue empty past this point

  // staging addresses: 16B chunk c of row r sourced from global chunk c^(r&7)
  const unsigned short* aptr[4];
  const unsigned short* bptr[4];
#pragma unroll
  for (int i = 0; i < 4; ++i) {
    int idx = i * 256 + t;
    int r = idx >> 3;
    int c = idx & 7;
    int cs = c ^ (r & 7);
    aptr[i] = xb + (size_t)ridx[r] * ND + cs * 8;
    bptr[i] = w1t + ((size_t)(e * NH + nt * 128 + r)) * ND + cs * 8;
  }

  f32x4 acc[4][4];
#pragma unroll
  for (int m = 0; m < 4; ++m)
#pragma unroll
    for (int n = 0; n < 4; ++n) acc[m][n] = (f32x4){0.f, 0.f, 0.f, 0.f};

  int arow = (wr * 64 + (lane & 15)) * 64;
  int brow = (wc * 64 + (lane & 15)) * 64;
  int sx = lane & 7;

  // prologue: tiles 0,1 in flight; vmcnt(8) retires exactly tile 0.
  STAGE(As0, Bs0, 0);
  STAGE(As1, Bs1, 64);
  asm volatile("s_waitcnt vmcnt(8)" ::: "memory");
  __builtin_amdgcn_s_barrier();

  // 16 K-tiles; phase pair consumes tiles 2i (buf0), 2i+1 (buf1) and stages
  // 2i+2 / 2i+3. Tail (it=7) re-stages the tiles being consumed (identical
  // bytes, L1/L2-hot, never re-read from HBM).
#pragma unroll 1
  for (int it = 0; it < 8; ++it) {
    int kt2 = (it < 7 ? it + 1 : it) * 128;
    PHASE(As0, Bs0, kt2);
    PHASE(As1, Bs1, kt2 + 64);
  }
  asm volatile("s_waitcnt vmcnt(0)" ::: "memory");  // drain tail prefetches

  // Epilogue: h = relu(acc + b1); partial[wi][nt][wc][row][c] = this wave's
  // 64-h-col contribution.  C/D frag: col=lane&15, row=(lane>>4)*4+i [m89].
  float* pbase = partial + (((size_t)(wi * 16 + nt)) * 2 + wc) * 128 * NC;
#pragma unroll
  for (int m = 0; m < 4; ++m) {
#pragma unroll
    for (int i = 0; i < 4; ++i) {
      float s0 = 0.f, s1 = 0.f, s2 = 0.f;
#pragma unroll
      for (int n = 0; n < 4; ++n) {
        float h = acc[m][n][i] + b1v[n];
        h = h > 0.f ? h : 0.f;
        s0 = fmaf(h, w2v[n][0], s0);
        s1 = fmaf(h, w2v[n][1], s1);
        s2 = fmaf(h, w2v[n][2], s2);
      }
#pragma unroll
      for (int d = 1; d < 16; d <<= 1) {
        s0 += __shfl_xor(s0, d);
        s1 += __shfl_xor(s1, d);
        s2 += __shfl_xor(s2, d);
      }
      if (cg == 0) {
        int rloc = wr * 64 + m * 16 + g * 4 + i;
        float* pp = pbase + rloc * NC;
        pp[0] = s0;
        pp[1] = s1;
        pp[2] = s2;
      }
    }
  }
}

// ---------------------------------------------------------------------------
// Kernel 4: reduce partials over (nt, wc) and write out = b2[e] + sum.
// One block per worklist tile; 384 threads = (row,c) pairs; sum 32 slots.
// ---------------------------------------------------------------------------
__global__ __launch_bounds__(384) void reduce_kernel(
    const float* __restrict__ partial, const float* __restrict__ b2,
    const int* __restrict__ perm, const int* __restrict__ counts,
    const int* __restrict__ offsets, const int* __restrict__ worklist,
    const int* __restrict__ n_wl, float* __restrict__ out) {
  int wi = blockIdx.x;
  if (wi >= *n_wl) return;
  int item = worklist[wi];
  int e = item >> 16;
  int mt = item & 0xffff;
  int cnt = counts[e];
  int off = offsets[e];
  int j = threadIdx.x;  // row*3 + c
  int r = j / 3, c = j - r * 3;
  int m = mt * 128 + r;
  if (m >= cnt) return;
  const float* p = partial + (size_t)wi * 32 * 384 + j;
  float s = 0.f;
#pragma unroll
  for (int q = 0; q < 32; ++q) s += p[q * 384];
  int tok = perm[off + m];
  out[tok * NC + c] = b2[e * NC + c] + s;
}

// ---------------------------------------------------------------------------
// Workspace layout (~74 MB):
//   [0,   32MiB)       xb  bf16 [16384][1024]
//   [32,  64MiB)       W1T bf16 [8][2048][1024]
//   [64MiB, +132KB)    topics[16384], perm[16384], counts[8], offsets[8],
//                      worklist[256], n_wl
//   [64MiB+132KB, ...) partial f32 [136*16][2][128][3]  (6.68 MB)
// (duplicate tail rows produce partials for rloc>=cnt; reduce guards.)
// ---------------------------------------------------------------------------
extern "C" void kernel_launch(void* const* d_in, const int* in_sizes, int n_in,
                              void* d_out, int out_size, void* d_ws,
                              size_t ws_size, hipStream_t stream) {
  const float* x = (const float*)d_in[0];
  const float* Wr = (const float*)d_in[1];
  const float* br = (const float*)d_in[2];
  const float* W1 = (const float*)d_in[3];
  const float* b1 = (const float*)d_in[4];
  const float* W2 = (const float*)d_in[5];
  const float* b2 = (const float*)d_in[6];
  float* out = (float*)d_out;

  char* ws = (char*)d_ws;
  unsigned short* xb = (unsigned short*)ws;
  unsigned short* w1t = (unsigned short*)(ws + (size_t)33554432);
  int* topics = (int*)(ws + (size_t)67108864);
  int* perm = topics + NB;
  int* counts = perm + NB;
  int* offsets = counts + NE;
  int* worklist = offsets + NE;
  int* n_wl = worklist + 256;
  float* partial = (float*)(ws + (size_t)67108864 + 135168);

  router_kernel<<<NB / 16, 256, 0, stream>>>(x, Wr, br, xb, topics);
  ranker_w1t_kernel<<<513, 1024, 0, stream>>>(topics, W1, w1t, perm, counts,
                                              offsets, worklist, n_wl);
  moe_gemm_kernel<<<MAXWL * 16, 256, 0, stream>>>(xb, w1t, b1, W2, perm,
                                                  counts, offsets, worklist,
                                                  n_wl, partial);
  reduce_kernel<<<MAXWL, 384, 0, stream>>>(partial, b2, perm, counts, offsets,
                                           worklist, n_wl, out);
}

// Round 17
// 163.915 us; speedup vs baseline: 1.0503x; 1.0503x over previous
//
#include <hip/hip_runtime.h>
#include <hip/hip_bf16.h>
#include <stdint.h>

// Problem dims (fixed by reference)
#define NB 16384
#define ND 1024
#define NH 2048
#define NE 8
#define NC 3
#define MAXWL 136  // max active (e,mt) 128-row tiles: 16384/128 + 8

typedef __attribute__((ext_vector_type(8))) short short8;
typedef __attribute__((ext_vector_type(4))) short short4v;
typedef __attribute__((ext_vector_type(4))) float f32x4;

// fp32 -> bf16 round-to-nearest-even
__device__ __forceinline__ unsigned short f2bf(float f) {
  union { float f; unsigned int u; } v; v.f = f;
  unsigned int u = v.u;
  return (unsigned short)((u + 0x7fffu + ((u >> 16) & 1u)) >> 16);
}

// async global->LDS, 16B per lane (LDS dest linear in lane order)
__device__ __forceinline__ void glds16(const void* g, void* l) {
  __builtin_amdgcn_global_load_lds(
      (const __attribute__((address_space(1))) void*)g,
      (__attribute__((address_space(3))) void*)l,
      16, 0, 0);
}

// ---------------------------------------------------------------------------
// Kernel 1: router. FOUR rows per wave: 16 x-loads in flight/thread, one Wr
// read serves 4 rows' FMAs. Fused x->bf16. fp32 logits (argmax must match
// numpy fp32). No atomics.
// ---------------------------------------------------------------------------
__global__ __launch_bounds__(256) void router_kernel(
    const float* __restrict__ x, const float* __restrict__ Wr,
    const float* __restrict__ br, unsigned short* __restrict__ xb,
    int* __restrict__ topics) {
  int w = threadIdx.x >> 6, lane = threadIdx.x & 63;
  int row0 = blockIdx.x * 16 + w * 4;
  const float* xr[4];
  unsigned short* xbr[4];
#pragma unroll
  for (int r = 0; r < 4; ++r) {
    xr[r] = x + (size_t)(row0 + r) * ND;
    xbr[r] = xb + (size_t)(row0 + r) * ND;
  }
  f32x4 xv[4][4];
#pragma unroll
  for (int r = 0; r < 4; ++r)
#pragma unroll
    for (int i = 0; i < 4; ++i)
      xv[r][i] = *(const f32x4*)(xr[r] + i * 256 + lane * 4);
  float p[4][NE];
#pragma unroll
  for (int r = 0; r < 4; ++r)
#pragma unroll
    for (int e = 0; e < NE; ++e) p[r][e] = 0.f;
#pragma unroll
  for (int i = 0; i < 4; ++i) {
    int k0 = i * 256 + lane * 4;
#pragma unroll
    for (int r = 0; r < 4; ++r) {
      short4v s;
#pragma unroll
      for (int j = 0; j < 4; ++j) s[j] = (short)f2bf(xv[r][i][j]);
      *(short4v*)(xbr[r] + k0) = s;  // coalesced 8B/lane
    }
#pragma unroll
    for (int j = 0; j < 4; ++j) {
      const f32x4* wp = (const f32x4*)(Wr + (size_t)(k0 + j) * NE);
      f32x4 wa = wp[0], wb = wp[1];  // one Wr read serves FOUR rows
#pragma unroll
      for (int r = 0; r < 4; ++r) {
        float a = xv[r][i][j];
        p[r][0] = fmaf(a, wa[0], p[r][0]);
        p[r][1] = fmaf(a, wa[1], p[r][1]);
        p[r][2] = fmaf(a, wa[2], p[r][2]);
        p[r][3] = fmaf(a, wa[3], p[r][3]);
        p[r][4] = fmaf(a, wb[0], p[r][4]);
        p[r][5] = fmaf(a, wb[1], p[r][5]);
        p[r][6] = fmaf(a, wb[2], p[r][6]);
        p[r][7] = fmaf(a, wb[3], p[r][7]);
      }
    }
  }
#pragma unroll
  for (int r = 0; r < 4; ++r)
#pragma unroll
    for (int e = 0; e < NE; ++e) {
#pragma unroll
      for (int d = 1; d < 64; d <<= 1) p[r][e] += __shfl_xor(p[r][e], d);
    }
  if (lane == 0) {
#pragma unroll
    for (int r = 0; r < 4; ++r) {
      float best = -1e30f;
      int bi = 0;
#pragma unroll
      for (int e = 0; e < NE; ++e) {
        float v = p[r][e] + br[e];
        if (v > best) { best = v; bi = e; }  // strict > : numpy argmax
      }
      topics[row0 + r] = bi;
    }
  }
}

// ---------------------------------------------------------------------------
// Kernel 2: FUSED ranker + W1 transpose (round-15 structure, kept).
//   blocks 0..511 : W1 [E][D][H] f32 -> W1T [E][H][D] bf16, 8 h-tiles each.
//   block  512    : ranker — packed-u16 Hillis-Steele scan -> stable rank
//                   -> perm scatter + counts/offsets + worklist.
// ---------------------------------------------------------------------------
__global__ __launch_bounds__(1024) void ranker_w1t_kernel(
    const int* __restrict__ topics, const float* __restrict__ W1,
    unsigned short* __restrict__ w1t, int* __restrict__ perm,
    int* __restrict__ counts, int* __restrict__ offsets,
    int* __restrict__ worklist, int* __restrict__ n_wl) {
  __shared__ __align__(16) char smem[8 * 64 * 67 * 2];  // 68.6KB, aliased
  __shared__ int soff[NE];
  int tid = threadIdx.x;

  if (blockIdx.x < 512) {
    // ---- W1 transpose+convert: eight 64x64 tiles (same e,kb; hb0..hb0+7) --
    unsigned short(*sbuf_t)[64][67] = (unsigned short(*)[64][67])smem;
    int bid = blockIdx.x;
    int e = bid >> 6;          // 64 blocks/expert
    int rem = bid & 63;
    int kb = rem >> 2;         // 16 k-tiles
    int hb0 = (rem & 3) * 8;   // 4 groups of 8 h-tiles
    int kl = tid >> 4;
    int h0 = (tid & 15) * 4;
    const float* src = W1 + ((size_t)e * ND + kb * 64) * NH + hb0 * 64;
    f32x4 v[8];
#pragma unroll
    for (int q = 0; q < 8; ++q)  // 8 independent loads in flight
      v[q] = *(const f32x4*)(src + (size_t)kl * NH + q * 64 + h0);
#pragma unroll
    for (int q = 0; q < 8; ++q) {
#pragma unroll
      for (int j = 0; j < 4; ++j) sbuf_t[q][kl][h0 + j] = f2bf(v[q][j]);
    }
    __syncthreads();
    // store: 4 (tile,pos) pairs per thread; wave writes 8 rows x 128B
    // contiguous segments (16B/lane coalesced).
#pragma unroll
    for (int s = 0; s < 4; ++s) {
      int flat = s * 1024 + tid;
      int q = flat >> 9;         // 0..7
      int idx = flat & 511;
      int hl = idx >> 3;         // 0..63
      int c8 = (idx & 7) * 8;    // k-chunk base
      short8 sv;
#pragma unroll
      for (int j = 0; j < 8; ++j) sv[j] = (short)sbuf_t[q][c8 + j][hl];
      unsigned short* dst =
          w1t + ((size_t)e * NH + (hb0 + q) * 64 + hl) * ND + kb * 64 + c8;
      *(short8*)dst = sv;  // 16B/lane
    }
    return;
  }

  // ---- ranker (block 512; scan buffer aliases smem) ----
  uint4* sbuf = (uint4*)smem;  // 16KB of the 68.6KB region
  int t[16];
  const int4* tp = (const int4*)(topics + tid * 16);
#pragma unroll
  for (int i = 0; i < 4; ++i) {
    int4 v = tp[i];
    t[i * 4 + 0] = v.x; t[i * 4 + 1] = v.y;
    t[i * 4 + 2] = v.z; t[i * 4 + 3] = v.w;
  }
  int h[NE] = {0, 0, 0, 0, 0, 0, 0, 0};
#pragma unroll
  for (int i = 0; i < 16; ++i) {
#pragma unroll
    for (int q = 0; q < NE; ++q) h[q] += (t[i] == q);
  }
  uint4 pk;
  pk.x = (unsigned)h[0] | ((unsigned)h[1] << 16);
  pk.y = (unsigned)h[2] | ((unsigned)h[3] << 16);
  pk.z = (unsigned)h[4] | ((unsigned)h[5] << 16);
  pk.w = (unsigned)h[6] | ((unsigned)h[7] << 16);
  uint4 own = pk;
  sbuf[tid] = pk;
  __syncthreads();
  for (int d = 1; d < 1024; d <<= 1) {
    uint4 v = {0u, 0u, 0u, 0u};
    if (tid >= d) v = sbuf[tid - d];
    __syncthreads();
    pk.x += v.x; pk.y += v.y; pk.z += v.z; pk.w += v.w;
    sbuf[tid] = pk;
    __syncthreads();
  }
  if (tid == 0) {
    uint4 tot = sbuf[1023];
    int c[NE] = {(int)(tot.x & 0xffff), (int)(tot.x >> 16),
                 (int)(tot.y & 0xffff), (int)(tot.y >> 16),
                 (int)(tot.z & 0xffff), (int)(tot.z >> 16),
                 (int)(tot.w & 0xffff), (int)(tot.w >> 16)};
    int s = 0, nw = 0;
    for (int e = 0; e < NE; ++e) {
      counts[e] = c[e];
      offsets[e] = s;
      soff[e] = s;
      s += c[e];
      for (int mt = 0; mt * 128 < c[e]; ++mt) worklist[nw++] = (e << 16) | mt;
    }
    *n_wl = nw;
  }
  __syncthreads();
  uint4 ex;
  ex.x = pk.x - own.x; ex.y = pk.y - own.y;
  ex.z = pk.z - own.z; ex.w = pk.w - own.w;
  int r[NE] = {soff[0] + (int)(ex.x & 0xffff), soff[1] + (int)(ex.x >> 16),
               soff[2] + (int)(ex.y & 0xffff), soff[3] + (int)(ex.y >> 16),
               soff[4] + (int)(ex.z & 0xffff), soff[5] + (int)(ex.z >> 16),
               soff[6] + (int)(ex.w & 0xffff), soff[7] + (int)(ex.w >> 16)};
#pragma unroll
  for (int i = 0; i < 16; ++i) {
    int e = t[i];
    int pos = 0;
#pragma unroll
    for (int q = 0; q < NE; ++q) pos = (e == q) ? r[q] : pos;
    perm[pos] = tid * 16 + i;
#pragma unroll
    for (int q = 0; q < NE; ++q) r[q] += (e == q);
  }
}

// ---------------------------------------------------------------------------
// Kernel 3: fused gathered GEMM + bias/relu + W2 reduce -> PARTIALS.
// Round-15's counted-vmcnt pipeline, REVERTED verbatim (best measured:
// 103.5us across 7 schedule variants; round-16's post-MFMA-drain reorder
// regressed to 113 — the pre-MFMA drain lets each wave enter its MFMA burst
// with operands resident while the co-resident block computes).
//   reads(buf[p]) ; lgkmcnt(0)+sched_barrier ; s_barrier(all-read) ;
//   STAGE(buf[p], t+2) ; setprio(1) MFMA setprio(0) ;
//   vmcnt(8) (retires buf[p^1]'s loads) ; s_barrier ; p^=1
// 128x128 tile, BK=64, 16 K-tiles, 4 waves; swizzle slot(r,c)=chunk c^(r&7).
// Tail (it=7) re-stages the tiles being consumed (L1/L2-hot, race-safe).
// ---------------------------------------------------------------------------
#define MF(a, b, c) __builtin_amdgcn_mfma_f32_16x16x32_bf16((a), (b), (c), 0, 0, 0)

#define STAGE(AS, BS, kt)                                         \
  do {                                                            \
    _Pragma("unroll") for (int i_ = 0; i_ < 4; ++i_) {            \
      glds16(aptr[i_] + (kt), (char*)(AS) + (i_ * 256 + t) * 16); \
      glds16(bptr[i_] + (kt), (char*)(BS) + (i_ * 256 + t) * 16); \
    }                                                             \
  } while (0)

// One phase: consume tile resident in (AS,BS); prefetch tile t+2 into the
// SAME buffers (safe: prefetch is issued after the all-read barrier).
#define PHASE(AS, BS, KT2)                                            \
  {                                                                   \
    short8 af_[2][4], bf_[2][4];                                      \
    _Pragma("unroll") for (int kk_ = 0; kk_ < 2; ++kk_) {             \
      int ch_ = ((kk_ * 4 + g) ^ sx) * 8;                             \
      _Pragma("unroll") for (int m_ = 0; m_ < 4; ++m_)                \
          af_[kk_][m_] = *(const short8*)&(AS)[arow + m_ * 1024 + ch_]; \
      _Pragma("unroll") for (int n_ = 0; n_ < 4; ++n_)                \
          bf_[kk_][n_] = *(const short8*)&(BS)[brow + n_ * 1024 + ch_]; \
    }                                                                 \
    asm volatile("s_waitcnt lgkmcnt(0)" ::: "memory");                \
    __builtin_amdgcn_sched_barrier(0);                                \
    __builtin_amdgcn_s_barrier();                                     \
    STAGE(AS, BS, KT2);                                               \
    __builtin_amdgcn_s_setprio(1);                                    \
    _Pragma("unroll") for (int kk_ = 0; kk_ < 2; ++kk_)               \
        _Pragma("unroll") for (int m_ = 0; m_ < 4; ++m_)              \
            _Pragma("unroll") for (int n_ = 0; n_ < 4; ++n_)          \
                acc[m_][n_] = MF(af_[kk_][m_], bf_[kk_][n_], acc[m_][n_]); \
    __builtin_amdgcn_s_setprio(0);                                    \
    asm volatile("s_waitcnt vmcnt(8)" ::: "memory");                  \
    __builtin_amdgcn_s_barrier();                                     \
  }

__global__ __launch_bounds__(256, 2) void moe_gemm_kernel(
    const unsigned short* __restrict__ xb, const unsigned short* __restrict__ w1t,
    const float* __restrict__ b1, const float* __restrict__ W2,
    const int* __restrict__ perm, const int* __restrict__ counts,
    const int* __restrict__ offsets, const int* __restrict__ worklist,
    const int* __restrict__ n_wl, float* __restrict__ partial) {
  int nt = blockIdx.x & 15;  // B panel; XCD = bid%8 -> B L2-local
  int wi = blockIdx.x >> 4;
  if (wi >= *n_wl) return;
  int item = worklist[wi];
  int e = item >> 16;
  int mt = item & 0xffff;
  int cnt = counts[e];
  int off = offsets[e];
  int t = threadIdx.x;
  int lane = t & 63;
  int w = t >> 6, wr = w >> 1, wc = w & 1;

  __shared__ int ridx[128];
  __shared__ unsigned short As0[128 * 64];  // slot(r,c) holds chunk c^(r&7)
  __shared__ unsigned short Bs0[128 * 64];
  __shared__ unsigned short As1[128 * 64];
  __shared__ unsigned short Bs1[128 * 64];

  if (t < 128) {
    int m = mt * 128 + t;
    ridx[t] = perm[off + (m < cnt ? m : cnt - 1)];
  }

  // Epilogue weights loaded & pinned BEFORE the __syncthreads drain, so the
  // K-loop's counted vmcnt(8) sees ONLY glds16 ops in the vmcnt queue.
  int cg = lane & 15;
  int g = lane >> 4;
  float b1v[4];
  float w2v[4][3];
#pragma unroll
  for (int n = 0; n < 4; ++n) {
    int col = nt * 128 + wc * 64 + n * 16 + cg;
    b1v[n] = b1[e * NH + col];
    const float* w2p = W2 + ((size_t)e * NH + col) * NC;
    w2v[n][0] = w2p[0];
    w2v[n][1] = w2p[1];
    w2v[n][2] = w2p[2];
  }
  asm volatile("" ::"v"(b1v[0]), "v"(b1v[1]), "v"(b1v[2]), "v"(b1v[3]),
               "v"(w2v[0][0]), "v"(w2v[0][1]), "v"(w2v[0][2]), "v"(w2v[1][0]),
               "v"(w2v[1][1]), "v"(w2v[1][2]), "v"(w2v[2][0]), "v"(w2v[2][1]),
               "v"(w2v[2][2]), "v"(w2v[3][0]), "v"(w2v[3][1]), "v"(w2v[3][2]));
  __syncthreads();  // full drain: vmcnt queue empty past this point

  // staging addresses: 16B chunk c of row r sourced from global chunk c^(r&7)
  const unsigned short* aptr[4];
  const unsigned short* bptr[4];
#pragma unroll
  for (int i = 0; i < 4; ++i) {
    int idx = i * 256 + t;
    int r = idx >> 3;
    int c = idx & 7;
    int cs = c ^ (r & 7);
    aptr[i] = xb + (size_t)ridx[r] * ND + cs * 8;
    bptr[i] = w1t + ((size_t)(e * NH + nt * 128 + r)) * ND + cs * 8;
  }

  f32x4 acc[4][4];
#pragma unroll
  for (int m = 0; m < 4; ++m)
#pragma unroll
    for (int n = 0; n < 4; ++n) acc[m][n] = (f32x4){0.f, 0.f, 0.f, 0.f};

  int arow = (wr * 64 + (lane & 15)) * 64;
  int brow = (wc * 64 + (lane & 15)) * 64;
  int sx = lane & 7;

  // prologue: tiles 0,1 in flight; vmcnt(8) retires exactly tile 0.
  STAGE(As0, Bs0, 0);
  STAGE(As1, Bs1, 64);
  asm volatile("s_waitcnt vmcnt(8)" ::: "memory");
  __builtin_amdgcn_s_barrier();

  // 16 K-tiles; phase pair consumes tiles 2i (buf0), 2i+1 (buf1) and stages
  // 2i+2 / 2i+3. Tail (it=7) re-stages the tiles being consumed (identical
  // bytes, L1/L2-hot, never re-read from HBM).
#pragma unroll 1
  for (int it = 0; it < 8; ++it) {
    int kt2 = (it < 7 ? it + 1 : it) * 128;
    PHASE(As0, Bs0, kt2);
    PHASE(As1, Bs1, kt2 + 64);
  }
  asm volatile("s_waitcnt vmcnt(0)" ::: "memory");  // drain tail prefetches

  // Epilogue: h = relu(acc + b1); partial[wi][nt][wc][row][c] = this wave's
  // 64-h-col contribution.  C/D frag: col=lane&15, row=(lane>>4)*4+i [m89].
  float* pbase = partial + (((size_t)(wi * 16 + nt)) * 2 + wc) * 128 * NC;
#pragma unroll
  for (int m = 0; m < 4; ++m) {
#pragma unroll
    for (int i = 0; i < 4; ++i) {
      float s0 = 0.f, s1 = 0.f, s2 = 0.f;
#pragma unroll
      for (int n = 0; n < 4; ++n) {
        float h = acc[m][n][i] + b1v[n];
        h = h > 0.f ? h : 0.f;
        s0 = fmaf(h, w2v[n][0], s0);
        s1 = fmaf(h, w2v[n][1], s1);
        s2 = fmaf(h, w2v[n][2], s2);
      }
#pragma unroll
      for (int d = 1; d < 16; d <<= 1) {
        s0 += __shfl_xor(s0, d);
        s1 += __shfl_xor(s1, d);
        s2 += __shfl_xor(s2, d);
      }
      if (cg == 0) {
        int rloc = wr * 64 + m * 16 + g * 4 + i;
        float* pp = pbase + rloc * NC;
        pp[0] = s0;
        pp[1] = s1;
        pp[2] = s2;
      }
    }
  }
}

// ---------------------------------------------------------------------------
// Kernel 4: reduce partials over (nt, wc) and write out = b2[e] + sum.
// One block per worklist tile; 384 threads = (row,c) pairs; sum 32 slots.
// ---------------------------------------------------------------------------
__global__ __launch_bounds__(384) void reduce_kernel(
    const float* __restrict__ partial, const float* __restrict__ b2,
    const int* __restrict__ perm, const int* __restrict__ counts,
    const int* __restrict__ offsets, const int* __restrict__ worklist,
    const int* __restrict__ n_wl, float* __restrict__ out) {
  int wi = blockIdx.x;
  if (wi >= *n_wl) return;
  int item = worklist[wi];
  int e = item >> 16;
  int mt = item & 0xffff;
  int cnt = counts[e];
  int off = offsets[e];
  int j = threadIdx.x;  // row*3 + c
  int r = j / 3, c = j - r * 3;
  int m = mt * 128 + r;
  if (m >= cnt) return;
  const float* p = partial + (size_t)wi * 32 * 384 + j;
  float s = 0.f;
#pragma unroll
  for (int q = 0; q < 32; ++q) s += p[q * 384];
  int tok = perm[off + m];
  out[tok * NC + c] = b2[e * NC + c] + s;
}

// ---------------------------------------------------------------------------
// Workspace layout (~74 MB):
//   [0,   32MiB)       xb  bf16 [16384][1024]
//   [32,  64MiB)       W1T bf16 [8][2048][1024]
//   [64MiB, +132KB)    topics[16384], perm[16384], counts[8], offsets[8],
//                      worklist[256], n_wl
//   [64MiB+132KB, ...) partial f32 [136*16][2][128][3]  (6.68 MB)
// (duplicate tail rows produce partials for rloc>=cnt; reduce guards.)
// ---------------------------------------------------------------------------
extern "C" void kernel_launch(void* const* d_in, const int* in_sizes, int n_in,
                              void* d_out, int out_size, void* d_ws,
                              size_t ws_size, hipStream_t stream) {
  const float* x = (const float*)d_in[0];
  const float* Wr = (const float*)d_in[1];
  const float* br = (const float*)d_in[2];
  const float* W1 = (const float*)d_in[3];
  const float* b1 = (const float*)d_in[4];
  const float* W2 = (const float*)d_in[5];
  const float* b2 = (const float*)d_in[6];
  float* out = (float*)d_out;

  char* ws = (char*)d_ws;
  unsigned short* xb = (unsigned short*)ws;
  unsigned short* w1t = (unsigned short*)(ws + (size_t)33554432);
  int* topics = (int*)(ws + (size_t)67108864);
  int* perm = topics + NB;
  int* counts = perm + NB;
  int* offsets = counts + NE;
  int* worklist = offsets + NE;
  int* n_wl = worklist + 256;
  float* partial = (float*)(ws + (size_t)67108864 + 135168);

  router_kernel<<<NB / 16, 256, 0, stream>>>(x, Wr, br, xb, topics);
  ranker_w1t_kernel<<<513, 1024, 0, stream>>>(topics, W1, w1t, perm, counts,
                                              offsets, worklist, n_wl);
  moe_gemm_kernel<<<MAXWL * 16, 256, 0, stream>>>(xb, w1t, b1, W2, perm,
                                                  counts, offsets, worklist,
                                                  n_wl, partial);
  reduce_kernel<<<MAXWL, 384, 0, stream>>>(partial, b2, perm, counts, offsets,
                                           worklist, n_wl, out);
}

// Round 18
// 163.614 us; speedup vs baseline: 1.0522x; 1.0018x over previous
//
#include <hip/hip_runtime.h>
#include <hip/hip_bf16.h>
#include <stdint.h>

// Problem dims (fixed by reference)
#define NB 16384
#define ND 1024
#define NH 2048
#define NE 8
#define NC 3
#define MAXWL 136  // max active (e,mt) 128-row tiles: 16384/128 + 8

typedef __attribute__((ext_vector_type(8))) short short8;
typedef __attribute__((ext_vector_type(4))) short short4v;
typedef __attribute__((ext_vector_type(4))) float f32x4;

// fp32 -> bf16 round-to-nearest-even
__device__ __forceinline__ unsigned short f2bf(float f) {
  union { float f; unsigned int u; } v; v.f = f;
  unsigned int u = v.u;
  return (unsigned short)((u + 0x7fffu + ((u >> 16) & 1u)) >> 16);
}

// async global->LDS, 16B per lane (LDS dest linear in lane order)
__device__ __forceinline__ void glds16(const void* g, void* l) {
  __builtin_amdgcn_global_load_lds(
      (const __attribute__((address_space(1))) void*)g,
      (__attribute__((address_space(3))) void*)l,
      16, 0, 0);
}

// ---------------------------------------------------------------------------
// Kernel 1: router. FOUR rows per wave: 16 x-loads in flight/thread, one Wr
// read serves 4 rows' FMAs. Fused x->bf16. fp32 logits (argmax must match
// numpy fp32). No atomics.
// ---------------------------------------------------------------------------
__global__ __launch_bounds__(256) void router_kernel(
    const float* __restrict__ x, const float* __restrict__ Wr,
    const float* __restrict__ br, unsigned short* __restrict__ xb,
    int* __restrict__ topics) {
  int w = threadIdx.x >> 6, lane = threadIdx.x & 63;
  int row0 = blockIdx.x * 16 + w * 4;
  const float* xr[4];
  unsigned short* xbr[4];
#pragma unroll
  for (int r = 0; r < 4; ++r) {
    xr[r] = x + (size_t)(row0 + r) * ND;
    xbr[r] = xb + (size_t)(row0 + r) * ND;
  }
  f32x4 xv[4][4];
#pragma unroll
  for (int r = 0; r < 4; ++r)
#pragma unroll
    for (int i = 0; i < 4; ++i)
      xv[r][i] = *(const f32x4*)(xr[r] + i * 256 + lane * 4);
  float p[4][NE];
#pragma unroll
  for (int r = 0; r < 4; ++r)
#pragma unroll
    for (int e = 0; e < NE; ++e) p[r][e] = 0.f;
#pragma unroll
  for (int i = 0; i < 4; ++i) {
    int k0 = i * 256 + lane * 4;
#pragma unroll
    for (int r = 0; r < 4; ++r) {
      short4v s;
#pragma unroll
      for (int j = 0; j < 4; ++j) s[j] = (short)f2bf(xv[r][i][j]);
      *(short4v*)(xbr[r] + k0) = s;  // coalesced 8B/lane
    }
#pragma unroll
    for (int j = 0; j < 4; ++j) {
      const f32x4* wp = (const f32x4*)(Wr + (size_t)(k0 + j) * NE);
      f32x4 wa = wp[0], wb = wp[1];  // one Wr read serves FOUR rows
#pragma unroll
      for (int r = 0; r < 4; ++r) {
        float a = xv[r][i][j];
        p[r][0] = fmaf(a, wa[0], p[r][0]);
        p[r][1] = fmaf(a, wa[1], p[r][1]);
        p[r][2] = fmaf(a, wa[2], p[r][2]);
        p[r][3] = fmaf(a, wa[3], p[r][3]);
        p[r][4] = fmaf(a, wb[0], p[r][4]);
        p[r][5] = fmaf(a, wb[1], p[r][5]);
        p[r][6] = fmaf(a, wb[2], p[r][6]);
        p[r][7] = fmaf(a, wb[3], p[r][7]);
      }
    }
  }
#pragma unroll
  for (int r = 0; r < 4; ++r)
#pragma unroll
    for (int e = 0; e < NE; ++e) {
#pragma unroll
      for (int d = 1; d < 64; d <<= 1) p[r][e] += __shfl_xor(p[r][e], d);
    }
  if (lane == 0) {
#pragma unroll
    for (int r = 0; r < 4; ++r) {
      float best = -1e30f;
      int bi = 0;
#pragma unroll
      for (int e = 0; e < NE; ++e) {
        float v = p[r][e] + br[e];
        if (v > best) { best = v; bi = e; }  // strict > : numpy argmax
      }
      topics[row0 + r] = bi;
    }
  }
}

// ---------------------------------------------------------------------------
// Kernel 2: FUSED ranker + W1 transpose (round-15 structure, kept).
//   blocks 0..511 : W1 [E][D][H] f32 -> W1T [E][H][D] bf16, 8 h-tiles each.
//   block  512    : ranker — packed-u16 Hillis-Steele scan -> stable rank
//                   -> perm scatter + counts/offsets + worklist.
// ---------------------------------------------------------------------------
__global__ __launch_bounds__(1024) void ranker_w1t_kernel(
    const int* __restrict__ topics, const float* __restrict__ W1,
    unsigned short* __restrict__ w1t, int* __restrict__ perm,
    int* __restrict__ counts, int* __restrict__ offsets,
    int* __restrict__ worklist, int* __restrict__ n_wl) {
  __shared__ __align__(16) char smem[8 * 64 * 67 * 2];  // 68.6KB, aliased
  __shared__ int soff[NE];
  int tid = threadIdx.x;

  if (blockIdx.x < 512) {
    // ---- W1 transpose+convert: eight 64x64 tiles (same e,kb; hb0..hb0+7) --
    unsigned short(*sbuf_t)[64][67] = (unsigned short(*)[64][67])smem;
    int bid = blockIdx.x;
    int e = bid >> 6;          // 64 blocks/expert
    int rem = bid & 63;
    int kb = rem >> 2;         // 16 k-tiles
    int hb0 = (rem & 3) * 8;   // 4 groups of 8 h-tiles
    int kl = tid >> 4;
    int h0 = (tid & 15) * 4;
    const float* src = W1 + ((size_t)e * ND + kb * 64) * NH + hb0 * 64;
    f32x4 v[8];
#pragma unroll
    for (int q = 0; q < 8; ++q)  // 8 independent loads in flight
      v[q] = *(const f32x4*)(src + (size_t)kl * NH + q * 64 + h0);
#pragma unroll
    for (int q = 0; q < 8; ++q) {
#pragma unroll
      for (int j = 0; j < 4; ++j) sbuf_t[q][kl][h0 + j] = f2bf(v[q][j]);
    }
    __syncthreads();
    // store: 4 (tile,pos) pairs per thread; wave writes 8 rows x 128B
    // contiguous segments (16B/lane coalesced).
#pragma unroll
    for (int s = 0; s < 4; ++s) {
      int flat = s * 1024 + tid;
      int q = flat >> 9;         // 0..7
      int idx = flat & 511;
      int hl = idx >> 3;         // 0..63
      int c8 = (idx & 7) * 8;    // k-chunk base
      short8 sv;
#pragma unroll
      for (int j = 0; j < 8; ++j) sv[j] = (short)sbuf_t[q][c8 + j][hl];
      unsigned short* dst =
          w1t + ((size_t)e * NH + (hb0 + q) * 64 + hl) * ND + kb * 64 + c8;
      *(short8*)dst = sv;  // 16B/lane
    }
    return;
  }

  // ---- ranker (block 512; scan buffer aliases smem) ----
  uint4* sbuf = (uint4*)smem;  // 16KB of the 68.6KB region
  int t[16];
  const int4* tp = (const int4*)(topics + tid * 16);
#pragma unroll
  for (int i = 0; i < 4; ++i) {
    int4 v = tp[i];
    t[i * 4 + 0] = v.x; t[i * 4 + 1] = v.y;
    t[i * 4 + 2] = v.z; t[i * 4 + 3] = v.w;
  }
  int h[NE] = {0, 0, 0, 0, 0, 0, 0, 0};
#pragma unroll
  for (int i = 0; i < 16; ++i) {
#pragma unroll
    for (int q = 0; q < NE; ++q) h[q] += (t[i] == q);
  }
  uint4 pk;
  pk.x = (unsigned)h[0] | ((unsigned)h[1] << 16);
  pk.y = (unsigned)h[2] | ((unsigned)h[3] << 16);
  pk.z = (unsigned)h[4] | ((unsigned)h[5] << 16);
  pk.w = (unsigned)h[6] | ((unsigned)h[7] << 16);
  uint4 own = pk;
  sbuf[tid] = pk;
  __syncthreads();
  for (int d = 1; d < 1024; d <<= 1) {
    uint4 v = {0u, 0u, 0u, 0u};
    if (tid >= d) v = sbuf[tid - d];
    __syncthreads();
    pk.x += v.x; pk.y += v.y; pk.z += v.z; pk.w += v.w;
    sbuf[tid] = pk;
    __syncthreads();
  }
  if (tid == 0) {
    uint4 tot = sbuf[1023];
    int c[NE] = {(int)(tot.x & 0xffff), (int)(tot.x >> 16),
                 (int)(tot.y & 0xffff), (int)(tot.y >> 16),
                 (int)(tot.z & 0xffff), (int)(tot.z >> 16),
                 (int)(tot.w & 0xffff), (int)(tot.w >> 16)};
    int s = 0, nw = 0;
    for (int e = 0; e < NE; ++e) {
      counts[e] = c[e];
      offsets[e] = s;
      soff[e] = s;
      s += c[e];
      for (int mt = 0; mt * 128 < c[e]; ++mt) worklist[nw++] = (e << 16) | mt;
    }
    *n_wl = nw;
  }
  __syncthreads();
  uint4 ex;
  ex.x = pk.x - own.x; ex.y = pk.y - own.y;
  ex.z = pk.z - own.z; ex.w = pk.w - own.w;
  int r[NE] = {soff[0] + (int)(ex.x & 0xffff), soff[1] + (int)(ex.x >> 16),
               soff[2] + (int)(ex.y & 0xffff), soff[3] + (int)(ex.y >> 16),
               soff[4] + (int)(ex.z & 0xffff), soff[5] + (int)(ex.z >> 16),
               soff[6] + (int)(ex.w & 0xffff), soff[7] + (int)(ex.w >> 16)};
#pragma unroll
  for (int i = 0; i < 16; ++i) {
    int e = t[i];
    int pos = 0;
#pragma unroll
    for (int q = 0; q < NE; ++q) pos = (e == q) ? r[q] : pos;
    perm[pos] = tid * 16 + i;
#pragma unroll
    for (int q = 0; q < NE; ++q) r[q] += (e == q);
  }
}

// ---------------------------------------------------------------------------
// Kernel 3: fused gathered GEMM + bias/relu + W2 reduce -> PARTIALS.
// Round-18: PERSISTENT BLOCKS. Grid = exactly 512 (2/CU); each block loops
// items (wi*16+nt) with stride 512. Removes the 4.25-fill grid-quantization
// tail and amortizes per-block prologue ~4x. Inner pipeline is round-15's
// proven counted-vmcnt schedule, UNCHANGED:
//   reads(buf[p]) ; lgkmcnt(0)+sched_barrier ; s_barrier(all-read) ;
//   STAGE(buf[p], t+2) ; setprio(1) MFMA setprio(0) ;
//   vmcnt(8) (retires buf[p^1]'s loads) ; s_barrier ; p^=1
// New invariant: loop-top __syncthreads separates previous item's epilogue
// ridx reads from next item's ridx writes (and re-drains vmcnt to 0 so the
// counted vmcnt(8) bookkeeping restarts clean each item).
// 128x128 tile, BK=64, 16 K-tiles, 4 waves; swizzle slot(r,c)=chunk c^(r&7).
// Tail (it=7) re-stages the tiles being consumed (L1/L2-hot, race-safe).
// ---------------------------------------------------------------------------
#define MF(a, b, c) __builtin_amdgcn_mfma_f32_16x16x32_bf16((a), (b), (c), 0, 0, 0)

#define STAGE(AS, BS, kt)                                         \
  do {                                                            \
    _Pragma("unroll") for (int i_ = 0; i_ < 4; ++i_) {            \
      glds16(aptr[i_] + (kt), (char*)(AS) + (i_ * 256 + t) * 16); \
      glds16(bptr[i_] + (kt), (char*)(BS) + (i_ * 256 + t) * 16); \
    }                                                             \
  } while (0)

// One phase: consume tile resident in (AS,BS); prefetch tile t+2 into the
// SAME buffers (safe: prefetch is issued after the all-read barrier).
#define PHASE(AS, BS, KT2)                                            \
  {                                                                   \
    short8 af_[2][4], bf_[2][4];                                      \
    _Pragma("unroll") for (int kk_ = 0; kk_ < 2; ++kk_) {             \
      int ch_ = ((kk_ * 4 + g) ^ sx) * 8;                             \
      _Pragma("unroll") for (int m_ = 0; m_ < 4; ++m_)                \
          af_[kk_][m_] = *(const short8*)&(AS)[arow + m_ * 1024 + ch_]; \
      _Pragma("unroll") for (int n_ = 0; n_ < 4; ++n_)                \
          bf_[kk_][n_] = *(const short8*)&(BS)[brow + n_ * 1024 + ch_]; \
    }                                                                 \
    asm volatile("s_waitcnt lgkmcnt(0)" ::: "memory");                \
    __builtin_amdgcn_sched_barrier(0);                                \
    __builtin_amdgcn_s_barrier();                                     \
    STAGE(AS, BS, KT2);                                               \
    __builtin_amdgcn_s_setprio(1);                                    \
    _Pragma("unroll") for (int kk_ = 0; kk_ < 2; ++kk_)               \
        _Pragma("unroll") for (int m_ = 0; m_ < 4; ++m_)              \
            _Pragma("unroll") for (int n_ = 0; n_ < 4; ++n_)          \
                acc[m_][n_] = MF(af_[kk_][m_], bf_[kk_][n_], acc[m_][n_]); \
    __builtin_amdgcn_s_setprio(0);                                    \
    asm volatile("s_waitcnt vmcnt(8)" ::: "memory");                  \
    __builtin_amdgcn_s_barrier();                                     \
  }

__global__ __launch_bounds__(256, 2) void moe_gemm_kernel(
    const unsigned short* __restrict__ xb, const unsigned short* __restrict__ w1t,
    const float* __restrict__ b1, const float* __restrict__ W2,
    const int* __restrict__ perm, const int* __restrict__ counts,
    const int* __restrict__ offsets, const int* __restrict__ worklist,
    const int* __restrict__ n_wl, float* __restrict__ partial) {
  int t = threadIdx.x;
  int lane = t & 63;
  int w = t >> 6, wr = w >> 1, wc = w & 1;
  int cg = lane & 15;
  int g = lane >> 4;
  int arow = (wr * 64 + cg) * 64;
  int brow = (wc * 64 + cg) * 64;
  int sx = lane & 7;

  __shared__ int ridx[128];
  __shared__ unsigned short As0[128 * 64];  // slot(r,c) holds chunk c^(r&7)
  __shared__ unsigned short Bs0[128 * 64];
  __shared__ unsigned short As1[128 * 64];
  __shared__ unsigned short Bs1[128 * 64];

  int nitems = *n_wl * 16;

#pragma unroll 1
  for (int item = blockIdx.x; item < nitems; item += 512) {
    int nt = item & 15;  // same nt across this block's items (512%16==0)
    int wi = item >> 4;
    int it2 = worklist[wi];
    int e = it2 >> 16;
    int mt = it2 & 0xffff;
    int cnt = counts[e];
    int off = offsets[e];

    // separate previous item's epilogue ridx reads from this item's writes
    __syncthreads();
    if (t < 128) {
      int m = mt * 128 + t;
      ridx[t] = perm[off + (m < cnt ? m : cnt - 1)];
    }

    // Epilogue weights loaded & pinned BEFORE the __syncthreads drain, so
    // the K-loop's counted vmcnt(8) sees ONLY glds16 ops in flight.
    float b1v[4];
    float w2v[4][3];
#pragma unroll
    for (int n = 0; n < 4; ++n) {
      int col = nt * 128 + wc * 64 + n * 16 + cg;
      b1v[n] = b1[e * NH + col];
      const float* w2p = W2 + ((size_t)e * NH + col) * NC;
      w2v[n][0] = w2p[0];
      w2v[n][1] = w2p[1];
      w2v[n][2] = w2p[2];
    }
    asm volatile("" ::"v"(b1v[0]), "v"(b1v[1]), "v"(b1v[2]), "v"(b1v[3]),
                 "v"(w2v[0][0]), "v"(w2v[0][1]), "v"(w2v[0][2]),
                 "v"(w2v[1][0]), "v"(w2v[1][1]), "v"(w2v[1][2]),
                 "v"(w2v[2][0]), "v"(w2v[2][1]), "v"(w2v[2][2]),
                 "v"(w2v[3][0]), "v"(w2v[3][1]), "v"(w2v[3][2]));
    __syncthreads();  // full drain: vmcnt queue empty past this point

    // staging addresses: 16B chunk c of row r from global chunk c^(r&7)
    const unsigned short* aptr[4];
    const unsigned short* bptr[4];
#pragma unroll
    for (int i = 0; i < 4; ++i) {
      int idx = i * 256 + t;
      int r = idx >> 3;
      int c = idx & 7;
      int cs = c ^ (r & 7);
      aptr[i] = xb + (size_t)ridx[r] * ND + cs * 8;
      bptr[i] = w1t + ((size_t)(e * NH + nt * 128 + r)) * ND + cs * 8;
    }

    f32x4 acc[4][4];
#pragma unroll
    for (int m = 0; m < 4; ++m)
#pragma unroll
      for (int n = 0; n < 4; ++n) acc[m][n] = (f32x4){0.f, 0.f, 0.f, 0.f};

    // prologue: tiles 0,1 in flight; vmcnt(8) retires exactly tile 0.
    STAGE(As0, Bs0, 0);
    STAGE(As1, Bs1, 64);
    asm volatile("s_waitcnt vmcnt(8)" ::: "memory");
    __builtin_amdgcn_s_barrier();

    // 16 K-tiles; phase pair consumes tiles 2i (buf0), 2i+1 (buf1), stages
    // 2i+2 / 2i+3. Tail re-stages the consumed tiles (L1/L2-hot, safe).
#pragma unroll 1
    for (int it = 0; it < 8; ++it) {
      int kt2 = (it < 7 ? it + 1 : it) * 128;
      PHASE(As0, Bs0, kt2);
      PHASE(As1, Bs1, kt2 + 64);
    }
    asm volatile("s_waitcnt vmcnt(0)" ::: "memory");  // drain tail stages

    // Epilogue: h = relu(acc + b1); partial[wi][nt][wc][row][c].
    // C/D frag: col=lane&15, row=(lane>>4)*4+i [m89].
    float* pbase = partial + (((size_t)(wi * 16 + nt)) * 2 + wc) * 128 * NC;
#pragma unroll
    for (int m = 0; m < 4; ++m) {
#pragma unroll
      for (int i = 0; i < 4; ++i) {
        float s0 = 0.f, s1 = 0.f, s2 = 0.f;
#pragma unroll
        for (int n = 0; n < 4; ++n) {
          float h = acc[m][n][i] + b1v[n];
          h = h > 0.f ? h : 0.f;
          s0 = fmaf(h, w2v[n][0], s0);
          s1 = fmaf(h, w2v[n][1], s1);
          s2 = fmaf(h, w2v[n][2], s2);
        }
#pragma unroll
        for (int d = 1; d < 16; d <<= 1) {
          s0 += __shfl_xor(s0, d);
          s1 += __shfl_xor(s1, d);
          s2 += __shfl_xor(s2, d);
        }
        if (cg == 0) {
          int rloc = wr * 64 + m * 16 + g * 4 + i;
          float* pp = pbase + rloc * NC;
          pp[0] = s0;
          pp[1] = s1;
          pp[2] = s2;
        }
      }
    }
  }
}

// ---------------------------------------------------------------------------
// Kernel 4: reduce partials over (nt, wc) and write out = b2[e] + sum.
// One block per worklist tile; 384 threads = (row,c) pairs; sum 32 slots.
// ---------------------------------------------------------------------------
__global__ __launch_bounds__(384) void reduce_kernel(
    const float* __restrict__ partial, const float* __restrict__ b2,
    const int* __restrict__ perm, const int* __restrict__ counts,
    const int* __restrict__ offsets, const int* __restrict__ worklist,
    const int* __restrict__ n_wl, float* __restrict__ out) {
  int wi = blockIdx.x;
  if (wi >= *n_wl) return;
  int item = worklist[wi];
  int e = item >> 16;
  int mt = item & 0xffff;
  int cnt = counts[e];
  int off = offsets[e];
  int j = threadIdx.x;  // row*3 + c
  int r = j / 3, c = j - r * 3;
  int m = mt * 128 + r;
  if (m >= cnt) return;
  const float* p = partial + (size_t)wi * 32 * 384 + j;
  float s = 0.f;
#pragma unroll
  for (int q = 0; q < 32; ++q) s += p[q * 384];
  int tok = perm[off + m];
  out[tok * NC + c] = b2[e * NC + c] + s;
}

// ---------------------------------------------------------------------------
// Workspace layout (~74 MB):
//   [0,   32MiB)       xb  bf16 [16384][1024]
//   [32,  64MiB)       W1T bf16 [8][2048][1024]
//   [64MiB, +132KB)    topics[16384], perm[16384], counts[8], offsets[8],
//                      worklist[256], n_wl
//   [64MiB+132KB, ...) partial f32 [136*16][2][128][3]  (6.68 MB)
// (duplicate tail rows produce partials for rloc>=cnt; reduce guards.)
// ---------------------------------------------------------------------------
extern "C" void kernel_launch(void* const* d_in, const int* in_sizes, int n_in,
                              void* d_out, int out_size, void* d_ws,
                              size_t ws_size, hipStream_t stream) {
  const float* x = (const float*)d_in[0];
  const float* Wr = (const float*)d_in[1];
  const float* br = (const float*)d_in[2];
  const float* W1 = (const float*)d_in[3];
  const float* b1 = (const float*)d_in[4];
  const float* W2 = (const float*)d_in[5];
  const float* b2 = (const float*)d_in[6];
  float* out = (float*)d_out;

  char* ws = (char*)d_ws;
  unsigned short* xb = (unsigned short*)ws;
  unsigned short* w1t = (unsigned short*)(ws + (size_t)33554432);
  int* topics = (int*)(ws + (size_t)67108864);
  int* perm = topics + NB;
  int* counts = perm + NB;
  int* offsets = counts + NE;
  int* worklist = offsets + NE;
  int* n_wl = worklist + 256;
  float* partial = (float*)(ws + (size_t)67108864 + 135168);

  router_kernel<<<NB / 16, 256, 0, stream>>>(x, Wr, br, xb, topics);
  ranker_w1t_kernel<<<513, 1024, 0, stream>>>(topics, W1, w1t, perm, counts,
                                              offsets, worklist, n_wl);
  moe_gemm_kernel<<<512, 256, 0, stream>>>(xb, w1t, b1, W2, perm, counts,
                                           offsets, worklist, n_wl, partial);
  reduce_kernel<<<MAXWL, 384, 0, stream>>>(partial, b2, perm, counts, offsets,
                                           worklist, n_wl, out);
}

// Round 19
// 154.262 us; speedup vs baseline: 1.1160x; 1.0606x over previous
//
#include <hip/hip_runtime.h>
#include <hip/hip_bf16.h>
#include <stdint.h>

// Problem dims (fixed by reference)
#define NB 16384
#define ND 1024
#define NH 2048
#define NE 8
#define NC 3
#define MAXWL 136  // max active (e,mt) 128-row tiles: 16384/128 + 8

typedef __attribute__((ext_vector_type(8))) short short8;
typedef __attribute__((ext_vector_type(4))) short short4v;
typedef __attribute__((ext_vector_type(4))) float f32x4;

// fp32 -> bf16 round-to-nearest-even
__device__ __forceinline__ unsigned short f2bf(float f) {
  union { float f; unsigned int u; } v; v.f = f;
  unsigned int u = v.u;
  return (unsigned short)((u + 0x7fffu + ((u >> 16) & 1u)) >> 16);
}

// async global->LDS, 16B per lane (LDS dest linear in lane order)
__device__ __forceinline__ void glds16(const void* g, void* l) {
  __builtin_amdgcn_global_load_lds(
      (const __attribute__((address_space(1))) void*)g,
      (__attribute__((address_space(3))) void*)l,
      16, 0, 0);
}

// ---------------------------------------------------------------------------
// Kernel 1: router. FOUR rows per wave: 16 x-loads in flight/thread, one Wr
// read serves 4 rows' FMAs. Fused x->bf16. fp32 logits (argmax must match
// numpy fp32). No atomics.
// ---------------------------------------------------------------------------
__global__ __launch_bounds__(256) void router_kernel(
    const float* __restrict__ x, const float* __restrict__ Wr,
    const float* __restrict__ br, unsigned short* __restrict__ xb,
    int* __restrict__ topics) {
  int w = threadIdx.x >> 6, lane = threadIdx.x & 63;
  int row0 = blockIdx.x * 16 + w * 4;
  const float* xr[4];
  unsigned short* xbr[4];
#pragma unroll
  for (int r = 0; r < 4; ++r) {
    xr[r] = x + (size_t)(row0 + r) * ND;
    xbr[r] = xb + (size_t)(row0 + r) * ND;
  }
  f32x4 xv[4][4];
#pragma unroll
  for (int r = 0; r < 4; ++r)
#pragma unroll
    for (int i = 0; i < 4; ++i)
      xv[r][i] = *(const f32x4*)(xr[r] + i * 256 + lane * 4);
  float p[4][NE];
#pragma unroll
  for (int r = 0; r < 4; ++r)
#pragma unroll
    for (int e = 0; e < NE; ++e) p[r][e] = 0.f;
#pragma unroll
  for (int i = 0; i < 4; ++i) {
    int k0 = i * 256 + lane * 4;
#pragma unroll
    for (int r = 0; r < 4; ++r) {
      short4v s;
#pragma unroll
      for (int j = 0; j < 4; ++j) s[j] = (short)f2bf(xv[r][i][j]);
      *(short4v*)(xbr[r] + k0) = s;  // coalesced 8B/lane
    }
#pragma unroll
    for (int j = 0; j < 4; ++j) {
      const f32x4* wp = (const f32x4*)(Wr + (size_t)(k0 + j) * NE);
      f32x4 wa = wp[0], wb = wp[1];  // one Wr read serves FOUR rows
#pragma unroll
      for (int r = 0; r < 4; ++r) {
        float a = xv[r][i][j];
        p[r][0] = fmaf(a, wa[0], p[r][0]);
        p[r][1] = fmaf(a, wa[1], p[r][1]);
        p[r][2] = fmaf(a, wa[2], p[r][2]);
        p[r][3] = fmaf(a, wa[3], p[r][3]);
        p[r][4] = fmaf(a, wb[0], p[r][4]);
        p[r][5] = fmaf(a, wb[1], p[r][5]);
        p[r][6] = fmaf(a, wb[2], p[r][6]);
        p[r][7] = fmaf(a, wb[3], p[r][7]);
      }
    }
  }
#pragma unroll
  for (int r = 0; r < 4; ++r)
#pragma unroll
    for (int e = 0; e < NE; ++e) {
#pragma unroll
      for (int d = 1; d < 64; d <<= 1) p[r][e] += __shfl_xor(p[r][e], d);
    }
  if (lane == 0) {
#pragma unroll
    for (int r = 0; r < 4; ++r) {
      float best = -1e30f;
      int bi = 0;
#pragma unroll
      for (int e = 0; e < NE; ++e) {
        float v = p[r][e] + br[e];
        if (v > best) { best = v; bi = e; }  // strict > : numpy argmax
      }
      topics[row0 + r] = bi;
    }
  }
}

// ---------------------------------------------------------------------------
// Kernel 2: FUSED ranker + W1 transpose (round-15 structure, kept).
//   blocks 0..511 : W1 [E][D][H] f32 -> W1T [E][H][D] bf16, 8 h-tiles each.
//   block  512    : ranker — packed-u16 Hillis-Steele scan -> stable rank
//                   -> perm scatter + counts/offsets + worklist.
// ---------------------------------------------------------------------------
__global__ __launch_bounds__(1024) void ranker_w1t_kernel(
    const int* __restrict__ topics, const float* __restrict__ W1,
    unsigned short* __restrict__ w1t, int* __restrict__ perm,
    int* __restrict__ counts, int* __restrict__ offsets,
    int* __restrict__ worklist, int* __restrict__ n_wl) {
  __shared__ __align__(16) char smem[8 * 64 * 67 * 2];  // 68.6KB, aliased
  __shared__ int soff[NE];
  int tid = threadIdx.x;

  if (blockIdx.x < 512) {
    // ---- W1 transpose+convert: eight 64x64 tiles (same e,kb; hb0..hb0+7) --
    unsigned short(*sbuf_t)[64][67] = (unsigned short(*)[64][67])smem;
    int bid = blockIdx.x;
    int e = bid >> 6;          // 64 blocks/expert
    int rem = bid & 63;
    int kb = rem >> 2;         // 16 k-tiles
    int hb0 = (rem & 3) * 8;   // 4 groups of 8 h-tiles
    int kl = tid >> 4;
    int h0 = (tid & 15) * 4;
    const float* src = W1 + ((size_t)e * ND + kb * 64) * NH + hb0 * 64;
    f32x4 v[8];
#pragma unroll
    for (int q = 0; q < 8; ++q)  // 8 independent loads in flight
      v[q] = *(const f32x4*)(src + (size_t)kl * NH + q * 64 + h0);
#pragma unroll
    for (int q = 0; q < 8; ++q) {
#pragma unroll
      for (int j = 0; j < 4; ++j) sbuf_t[q][kl][h0 + j] = f2bf(v[q][j]);
    }
    __syncthreads();
    // store: 4 (tile,pos) pairs per thread; wave writes 8 rows x 128B
    // contiguous segments (16B/lane coalesced).
#pragma unroll
    for (int s = 0; s < 4; ++s) {
      int flat = s * 1024 + tid;
      int q = flat >> 9;         // 0..7
      int idx = flat & 511;
      int hl = idx >> 3;         // 0..63
      int c8 = (idx & 7) * 8;    // k-chunk base
      short8 sv;
#pragma unroll
      for (int j = 0; j < 8; ++j) sv[j] = (short)sbuf_t[q][c8 + j][hl];
      unsigned short* dst =
          w1t + ((size_t)e * NH + (hb0 + q) * 64 + hl) * ND + kb * 64 + c8;
      *(short8*)dst = sv;  // 16B/lane
    }
    return;
  }

  // ---- ranker (block 512; scan buffer aliases smem) ----
  uint4* sbuf = (uint4*)smem;  // 16KB of the 68.6KB region
  int t[16];
  const int4* tp = (const int4*)(topics + tid * 16);
#pragma unroll
  for (int i = 0; i < 4; ++i) {
    int4 v = tp[i];
    t[i * 4 + 0] = v.x; t[i * 4 + 1] = v.y;
    t[i * 4 + 2] = v.z; t[i * 4 + 3] = v.w;
  }
  int h[NE] = {0, 0, 0, 0, 0, 0, 0, 0};
#pragma unroll
  for (int i = 0; i < 16; ++i) {
#pragma unroll
    for (int q = 0; q < NE; ++q) h[q] += (t[i] == q);
  }
  uint4 pk;
  pk.x = (unsigned)h[0] | ((unsigned)h[1] << 16);
  pk.y = (unsigned)h[2] | ((unsigned)h[3] << 16);
  pk.z = (unsigned)h[4] | ((unsigned)h[5] << 16);
  pk.w = (unsigned)h[6] | ((unsigned)h[7] << 16);
  uint4 own = pk;
  sbuf[tid] = pk;
  __syncthreads();
  for (int d = 1; d < 1024; d <<= 1) {
    uint4 v = {0u, 0u, 0u, 0u};
    if (tid >= d) v = sbuf[tid - d];
    __syncthreads();
    pk.x += v.x; pk.y += v.y; pk.z += v.z; pk.w += v.w;
    sbuf[tid] = pk;
    __syncthreads();
  }
  if (tid == 0) {
    uint4 tot = sbuf[1023];
    int c[NE] = {(int)(tot.x & 0xffff), (int)(tot.x >> 16),
                 (int)(tot.y & 0xffff), (int)(tot.y >> 16),
                 (int)(tot.z & 0xffff), (int)(tot.z >> 16),
                 (int)(tot.w & 0xffff), (int)(tot.w >> 16)};
    int s = 0, nw = 0;
    for (int e = 0; e < NE; ++e) {
      counts[e] = c[e];
      offsets[e] = s;
      soff[e] = s;
      s += c[e];
      for (int mt = 0; mt * 128 < c[e]; ++mt) worklist[nw++] = (e << 16) | mt;
    }
    *n_wl = nw;
  }
  __syncthreads();
  uint4 ex;
  ex.x = pk.x - own.x; ex.y = pk.y - own.y;
  ex.z = pk.z - own.z; ex.w = pk.w - own.w;
  int r[NE] = {soff[0] + (int)(ex.x & 0xffff), soff[1] + (int)(ex.x >> 16),
               soff[2] + (int)(ex.y & 0xffff), soff[3] + (int)(ex.y >> 16),
               soff[4] + (int)(ex.z & 0xffff), soff[5] + (int)(ex.z >> 16),
               soff[6] + (int)(ex.w & 0xffff), soff[7] + (int)(ex.w >> 16)};
#pragma unroll
  for (int i = 0; i < 16; ++i) {
    int e = t[i];
    int pos = 0;
#pragma unroll
    for (int q = 0; q < NE; ++q) pos = (e == q) ? r[q] : pos;
    perm[pos] = tid * 16 + i;
#pragma unroll
    for (int q = 0; q < NE; ++q) r[q] += (e == q);
  }
}

// ---------------------------------------------------------------------------
// Kernel 3: fused gathered GEMM + bias/relu + W2 reduce -> PARTIALS.
// Round-19: the untested m97 cell — BK=64 + SINGLE-buffered 33KB LDS +
// 3 blocks/CU + plain __syncthreads. Every prior variant missed one leg:
// r5 dbuf=66KB->2/CU; r8 BK=32 (half compute/barrier-period); r9-18
// counted-vmcnt at 2/CU. Model: K-step = stage(~100cy issue) + drain(~700cy)
// + compute(~320cy); 3 resident blocks cover each other's drains (m114) ->
// predicted MFMA util ~3x160/1100 ~ 44% vs measured 29%.
//   STAGE(kt) ; __syncthreads (drains vmcnt) ; COMPUTE ; __syncthreads
// 128x128 tile, 16 K-tiles, 4 waves; swizzle slot(r,c)=chunk c^(r&7).
// __launch_bounds__(256,3): unified 170-reg budget vs ~168 needed (104 VGPR
// + 64 AGPR) — WRITE_SIZE is the spill canary.
// ---------------------------------------------------------------------------
#define MF(a, b, c) __builtin_amdgcn_mfma_f32_16x16x32_bf16((a), (b), (c), 0, 0, 0)

#define STAGE(AS, BS, kt)                                         \
  do {                                                            \
    _Pragma("unroll") for (int i_ = 0; i_ < 4; ++i_) {            \
      glds16(aptr[i_] + (kt), (char*)(AS) + (i_ * 256 + t) * 16); \
      glds16(bptr[i_] + (kt), (char*)(BS) + (i_ * 256 + t) * 16); \
    }                                                             \
  } while (0)

#define COMPUTE(AS, BS)                                               \
  do {                                                                \
    _Pragma("unroll") for (int kk_ = 0; kk_ < 2; ++kk_) {             \
      int ch_ = ((kk_ * 4 + g) ^ sx) * 8;                             \
      short8 af_[4], bf_[4];                                          \
      _Pragma("unroll") for (int m_ = 0; m_ < 4; ++m_)                \
          af_[m_] = *(const short8*)&(AS)[arow + m_ * 1024 + ch_];    \
      _Pragma("unroll") for (int n_ = 0; n_ < 4; ++n_)                \
          bf_[n_] = *(const short8*)&(BS)[brow + n_ * 1024 + ch_];    \
      _Pragma("unroll") for (int m_ = 0; m_ < 4; ++m_)                \
          _Pragma("unroll") for (int n_ = 0; n_ < 4; ++n_)            \
              acc[m_][n_] = MF(af_[m_], bf_[n_], acc[m_][n_]);        \
    }                                                                 \
  } while (0)

__global__ __launch_bounds__(256, 3) void moe_gemm_kernel(
    const unsigned short* __restrict__ xb, const unsigned short* __restrict__ w1t,
    const float* __restrict__ b1, const float* __restrict__ W2,
    const int* __restrict__ perm, const int* __restrict__ counts,
    const int* __restrict__ offsets, const int* __restrict__ worklist,
    const int* __restrict__ n_wl, float* __restrict__ partial) {
  int nt = blockIdx.x & 15;  // B panel; XCD = bid%8 -> B L2-local
  int wi = blockIdx.x >> 4;
  if (wi >= *n_wl) return;
  int item = worklist[wi];
  int e = item >> 16;
  int mt = item & 0xffff;
  int cnt = counts[e];
  int off = offsets[e];
  int t = threadIdx.x;
  int lane = t & 63;
  int w = t >> 6, wr = w >> 1, wc = w & 1;

  __shared__ int ridx[128];
  __shared__ unsigned short As[128 * 64];  // slot(r,c) holds chunk c^(r&7)
  __shared__ unsigned short Bs[128 * 64];

  if (t < 128) {
    int m = mt * 128 + t;
    ridx[t] = perm[off + (m < cnt ? m : cnt - 1)];
  }

  // epilogue weights hoisted above the K-loop (L2-hot, hidden under MFMA)
  int cg = lane & 15;
  int g = lane >> 4;
  float b1v[4];
  float w2v[4][3];
#pragma unroll
  for (int n = 0; n < 4; ++n) {
    int col = nt * 128 + wc * 64 + n * 16 + cg;
    b1v[n] = b1[e * NH + col];
    const float* w2p = W2 + ((size_t)e * NH + col) * NC;
    w2v[n][0] = w2p[0];
    w2v[n][1] = w2p[1];
    w2v[n][2] = w2p[2];
  }
  __syncthreads();  // ridx visible

  // staging addresses: 16B chunk c of row r sourced from global chunk c^(r&7)
  const unsigned short* aptr[4];
  const unsigned short* bptr[4];
#pragma unroll
  for (int i = 0; i < 4; ++i) {
    int idx = i * 256 + t;
    int r = idx >> 3;
    int c = idx & 7;
    int cs = c ^ (r & 7);
    aptr[i] = xb + (size_t)ridx[r] * ND + cs * 8;
    bptr[i] = w1t + ((size_t)(e * NH + nt * 128 + r)) * ND + cs * 8;
  }

  f32x4 acc[4][4];
#pragma unroll
  for (int m = 0; m < 4; ++m)
#pragma unroll
    for (int n = 0; n < 4; ++n) acc[m][n] = (f32x4){0.f, 0.f, 0.f, 0.f};

  int arow = (wr * 64 + cg) * 64;
  int brow = (wc * 64 + cg) * 64;
  int sx = lane & 7;

  // single-buffered K-loop: 16 tiles of BK=64; __syncthreads drains vmcnt
  // before compute; second barrier protects the overwrite. 3 resident
  // blocks/CU overlap each other's stage-drains (m114).
#pragma unroll 1
  for (int kt = 0; kt < ND; kt += 64) {
    STAGE(As, Bs, kt);
    __syncthreads();
    COMPUTE(As, Bs);
    __syncthreads();
  }

  // Epilogue: h = relu(acc + b1); partial[wi][nt][wc][row][c] = this wave's
  // 64-h-col contribution.  C/D frag: col=lane&15, row=(lane>>4)*4+i [m89].
  float* pbase = partial + (((size_t)(wi * 16 + nt)) * 2 + wc) * 128 * NC;
#pragma unroll
  for (int m = 0; m < 4; ++m) {
#pragma unroll
    for (int i = 0; i < 4; ++i) {
      float s0 = 0.f, s1 = 0.f, s2 = 0.f;
#pragma unroll
      for (int n = 0; n < 4; ++n) {
        float h = acc[m][n][i] + b1v[n];
        h = h > 0.f ? h : 0.f;
        s0 = fmaf(h, w2v[n][0], s0);
        s1 = fmaf(h, w2v[n][1], s1);
        s2 = fmaf(h, w2v[n][2], s2);
      }
#pragma unroll
      for (int d = 1; d < 16; d <<= 1) {
        s0 += __shfl_xor(s0, d);
        s1 += __shfl_xor(s1, d);
        s2 += __shfl_xor(s2, d);
      }
      if (cg == 0) {
        int rloc = wr * 64 + m * 16 + g * 4 + i;
        float* pp = pbase + rloc * NC;
        pp[0] = s0;
        pp[1] = s1;
        pp[2] = s2;
      }
    }
  }
}

// ---------------------------------------------------------------------------
// Kernel 4: reduce partials over (nt, wc) and write out = b2[e] + sum.
// One block per worklist tile; 384 threads = (row,c) pairs; sum 32 slots.
// ---------------------------------------------------------------------------
__global__ __launch_bounds__(384) void reduce_kernel(
    const float* __restrict__ partial, const float* __restrict__ b2,
    const int* __restrict__ perm, const int* __restrict__ counts,
    const int* __restrict__ offsets, const int* __restrict__ worklist,
    const int* __restrict__ n_wl, float* __restrict__ out) {
  int wi = blockIdx.x;
  if (wi >= *n_wl) return;
  int item = worklist[wi];
  int e = item >> 16;
  int mt = item & 0xffff;
  int cnt = counts[e];
  int off = offsets[e];
  int j = threadIdx.x;  // row*3 + c
  int r = j / 3, c = j - r * 3;
  int m = mt * 128 + r;
  if (m >= cnt) return;
  const float* p = partial + (size_t)wi * 32 * 384 + j;
  float s = 0.f;
#pragma unroll
  for (int q = 0; q < 32; ++q) s += p[q * 384];
  int tok = perm[off + m];
  out[tok * NC + c] = b2[e * NC + c] + s;
}

// ---------------------------------------------------------------------------
// Workspace layout (~74 MB):
//   [0,   32MiB)       xb  bf16 [16384][1024]
//   [32,  64MiB)       W1T bf16 [8][2048][1024]
//   [64MiB, +132KB)    topics[16384], perm[16384], counts[8], offsets[8],
//                      worklist[256], n_wl
//   [64MiB+132KB, ...) partial f32 [136*16][2][128][3]  (6.68 MB)
// (duplicate tail rows produce partials for rloc>=cnt; reduce guards.)
// ---------------------------------------------------------------------------
extern "C" void kernel_launch(void* const* d_in, const int* in_sizes, int n_in,
                              void* d_out, int out_size, void* d_ws,
                              size_t ws_size, hipStream_t stream) {
  const float* x = (const float*)d_in[0];
  const float* Wr = (const float*)d_in[1];
  const float* br = (const float*)d_in[2];
  const float* W1 = (const float*)d_in[3];
  const float* b1 = (const float*)d_in[4];
  const float* W2 = (const float*)d_in[5];
  const float* b2 = (const float*)d_in[6];
  float* out = (float*)d_out;

  char* ws = (char*)d_ws;
  unsigned short* xb = (unsigned short*)ws;
  unsigned short* w1t = (unsigned short*)(ws + (size_t)33554432);
  int* topics = (int*)(ws + (size_t)67108864);
  int* perm = topics + NB;
  int* counts = perm + NB;
  int* offsets = counts + NE;
  int* worklist = offsets + NE;
  int* n_wl = worklist + 256;
  float* partial = (float*)(ws + (size_t)67108864 + 135168);

  router_kernel<<<NB / 16, 256, 0, stream>>>(x, Wr, br, xb, topics);
  ranker_w1t_kernel<<<513, 1024, 0, stream>>>(topics, W1, w1t, perm, counts,
                                              offsets, worklist, n_wl);
  moe_gemm_kernel<<<MAXWL * 16, 256, 0, stream>>>(xb, w1t, b1, W2, perm,
                                                  counts, offsets, worklist,
                                                  n_wl, partial);
  reduce_kernel<<<MAXWL, 384, 0, stream>>>(partial, b2, perm, counts, offsets,
                                           worklist, n_wl, out);
}